// Round 12
// baseline (625.762 us; speedup 1.0000x reference)
//
#include <hip/hip_runtime.h>

#define B_SZ  1024
#define NSEQ  512
#define D_INP 30
#define H     64
#define MB    4
#define L2E   1.4426950408889634f

typedef short s16x8 __attribute__((ext_vector_type(8)));
typedef float f32x4 __attribute__((ext_vector_type(4)));

#if __has_builtin(__builtin_amdgcn_exp2f)
#define EXP2(x) __builtin_amdgcn_exp2f(x)
#else
#define EXP2(x) exp2f(x)
#endif

__device__ __forceinline__ float rcp_f(float v) { return __builtin_amdgcn_rcpf(v); }

__device__ __forceinline__ f32x4 mfma16(s16x8 a, s16x8 b, f32x4 c) {
  return __builtin_amdgcn_mfma_f32_16x16x32_bf16(a, b, c, 0, 0, 0);
}

__device__ __forceinline__ short bf16_rne(float f) {
  unsigned u = __float_as_uint(f);
  unsigned r = (u + 0x7FFFu + ((u >> 16) & 1u)) >> 16;
  return (short)r;
}

__device__ __forceinline__ s16x8 rne8(const float* f) {
  s16x8 o;
#pragma unroll
  for (int i = 0; i < 8; ++i) o[i] = bf16_rne(f[i]);
  return o;
}

__device__ __forceinline__ void split8(const float* f, s16x8& hi, s16x8& lo) {
#pragma unroll
  for (int i = 0; i < 8; ++i) {
    unsigned ub = __float_as_uint(f[i]);
    hi[i] = (short)(ub >> 16);
    float hf = __uint_as_float(ub & 0xFFFF0000u);
    float lf = f[i] - hf;
    lo[i] = (short)(__float_as_uint(lf) >> 16);
  }
}

// ---------------------------------------------------------------------------
// Kernel A: fold FC into the input-side gate GEMM (fp32). 8 blocks.
// ---------------------------------------------------------------------------
__global__ __launch_bounds__(256) void prep_kernel(
    const float* __restrict__ W_fc, const float* __restrict__ b_fc,
    const float* __restrict__ W_ih, const float* __restrict__ b_ih,
    const float* __restrict__ b_hh,
    float* __restrict__ wsW, float* __restrict__ wsB) {
  __shared__ float fc[H * D_INP];
  __shared__ float bfc[H];
  const int u = threadIdx.x;
  for (int i = u; i < H * D_INP; i += 256) fc[i] = W_fc[i];
  if (u < H) bfc[u] = b_fc[u];
  __syncthreads();

  const int n = blockIdx.x * 32 + u;
  if (u < 32) {
    float wih[H];
#pragma unroll
    for (int i = 0; i < H; ++i) wih[i] = W_ih[n * H + i];

    for (int k = 0; k < D_INP; ++k) {
      float s = 0.f;
#pragma unroll
      for (int i = 0; i < H; ++i) s = fmaf(wih[i], fc[i * D_INP + k], s);
      wsW[n * 32 + k] = s;
    }
    wsW[n * 32 + 30] = 0.f;
    wsW[n * 32 + 31] = 0.f;

    float bb = b_ih[n] + b_hh[n];
#pragma unroll
    for (int i = 0; i < H; ++i) bb = fmaf(wih[i], bfc[i], bb);
    wsB[n] = bb;
  }
}

// ---------------------------------------------------------------------------
// Kernel B: MFMA LSTM, 256 blocks x 64 threads = ONE WAVE PER BLOCK.
// BATCH-SPLIT, BARRIER-FREE: the wave owns 4 batches ENTIRELY (all 256 gate
// rows), so the recurrence is wave-local. h round-trips through LDS within
// the same wave (in-order LDS pipe; no s_barrier anywhere in the loop).
// r5/r8-r11 proved the barrier phase-locks waves so no concurrency scheme
// overlaps the chain; this deletes the barrier instead.
// Layout: batch b at A/D row 4b -> liveness lives in the REG index (r=0),
// dead rows compile-time skipped (activation stays 4 unit-chains/lane).
// Per step: ds_read h-frags (latency hidden under...) -> 16 acc-init MFMAs
// (bias+x, h-independent) -> 32 gate MFMAs -> 4 logit MFMAs -> activation
// -> 4 ds_write_b16. x is loaded DIRECTLY from global (8 floats/lane ->
// rne8 -> A-frag; same bf16 values as staged path), 2-step lookahead.
// Weights: 48 s16x8 frags (~192 regs) -> gfx950 unified VGPR/AGPR file
// (launch_bounds(64,1)); MFMA reads operands from AGPR natively.
// Live products / accumulation order bit-identical to round 4
// -> absmax must stay exactly 1.525879e-05. Canary: WRITE_SIZE ~2048 KB
// (any scratch spill invalidates the experiment).
// ---------------------------------------------------------------------------
__global__ __launch_bounds__(64, 1) void lstm_mfma(
    const float* __restrict__ x, const float* __restrict__ W_hh,
    const float* __restrict__ wsW, const float* __restrict__ wsB,
    const float* __restrict__ W_last, float* __restrict__ out) {

  __shared__ short hpl[16][74];                 // h plane, rows 4b live
  __shared__ float logitsT[NSEQ + 1][MB];       // 8.2 KB

  const int l   = threadIdx.x;   // 0..63
  const int low = l & 15;
  const int q   = l >> 4;
  const int b0  = blockIdx.x * MB;

  // ---- B-frags for all 16 (gate, col-block) tiles ----
  // gate order: 0=i, 1=f, 2=g, 3=o ; unit n = 64*jg + 16*jb + low.
  s16x8 whh[4][4][2], wcb[4][4];
  float xb[4][4];
  s16x8 wl_h[2], wl_l[2];
  {
    float tmp[8];
#pragma unroll
    for (int jg = 0; jg < 4; ++jg) {
#pragma unroll
      for (int jb = 0; jb < 4; ++jb) {
        const int n = 64 * jg + 16 * jb + low;
        const float sc = (jg == 2) ? (2.0f * L2E) : L2E;
#pragma unroll
        for (int kt = 0; kt < 2; ++kt) {
          const float* p = W_hh + n * H + kt * 32 + q * 8;
#pragma unroll
          for (int j = 0; j < 8; ++j) tmp[j] = p[j] * sc;
          whh[jg][jb][kt] = rne8(tmp);
        }
        const float* pw = wsW + n * 32 + q * 8;
#pragma unroll
        for (int j = 0; j < 8; ++j) tmp[j] = pw[j] * sc;
        wcb[jg][jb] = rne8(tmp);
        xb[jg][jb] = wsB[n] * sc;
      }
    }
#pragma unroll
    for (int kt = 0; kt < 2; ++kt) {
#pragma unroll
      for (int j = 0; j < 8; ++j)
        tmp[j] = (low == 0) ? W_last[kt * 32 + q * 8 + j] : 0.0f;
      split8(tmp, wl_h[kt], wl_l[kt]);
    }
  }

  // zero h plane (h(-1)=0; dead rows stay zero forever)
  for (int i = l; i < 16 * 74 / 2; i += 64) ((int*)hpl)[i] = 0;
  asm volatile("s_waitcnt lgkmcnt(0)" ::: "memory");

  // ---- x direct-from-global pipeline (2-step lookahead) ----
  // every lane loads batch (low>>2); dead rows feed dead D rows (finite).
  const float* xrow = x + (size_t)(b0 + (low >> 2)) * NSEQ * D_INP + q * 8;
  float2 v0, v1, v2, v3;
  auto xload = [&](int t) {
    const float* p = xrow + (size_t)t * D_INP;
    v0 = *(const float2*)(p);
    v1 = *(const float2*)(p + 2);
    v2 = *(const float2*)(p + 4);
    v3 = (q < 3) ? *(const float2*)(p + 6) : make_float2(0.f, 0.f);
  };
  auto xconv = [&]() {
    float tmp[8] = {v0.x, v0.y, v1.x, v1.y, v2.x, v2.y, v3.x, v3.y};
    return rne8(tmp);
  };

  xload(0);
  s16x8 ax = xconv();          // a_x(0)
  xload(1);

  float c4[4] = {0.f, 0.f, 0.f, 0.f};   // cell state, 4 units/lane

  for (int t = 0; t < NSEQ; ++t) {
    // ---- h(t-1) A-frags: row = low (batch rows 4b live, others zero) ----
    const short* hp = &hpl[low][0];
    s16x8 ah0 = *(const s16x8*)(hp + q * 8);
    s16x8 ah1 = *(const s16x8*)(hp + 32 + q * 8);

    // ---- acc init: bias + x side (no h dependency; hides ds_read) ----
    f32x4 acc[4][4];
#pragma unroll
    for (int jg = 0; jg < 4; ++jg)
#pragma unroll
      for (int jb = 0; jb < 4; ++jb) {
        f32x4 bi = {xb[jg][jb], xb[jg][jb], xb[jg][jb], xb[jg][jb]};
        acc[jg][jb] = mfma16(ax, wcb[jg][jb], bi);
      }

    // ---- gate MFMAs: two K-passes, r4 accumulation order ----
#pragma unroll
    for (int jg = 0; jg < 4; ++jg)
#pragma unroll
      for (int jb = 0; jb < 4; ++jb)
        acc[jg][jb] = mfma16(ah0, whh[jg][jb][0], acc[jg][jb]);
#pragma unroll
    for (int jg = 0; jg < 4; ++jg)
#pragma unroll
      for (int jb = 0; jb < 4; ++jb)
        acc[jg][jb] = mfma16(ah1, whh[jg][jb][1], acc[jg][jb]);

    // ---- logit of h(t-1) ----
    {
      const f32x4 z = {0.f, 0.f, 0.f, 0.f};
      f32x4 aL = mfma16(ah0, wl_h[0], z);
      aL = mfma16(ah1, wl_h[1], aL);
      f32x4 bL = mfma16(ah0, wl_l[0], z);
      bL = mfma16(ah1, wl_l[1], bL);
      float lg = aL[0] + bL[0];
      if (low == 0) logitsT[t][q] = lg;
    }

    // ---- x pipeline: convert x(t+1), issue load x(t+2) ----
    s16x8 axn = xconv();
    {
      const int tld = (t + 2 < NSEQ) ? t + 2 : NSEQ - 1;
      xload(tld);
    }

    // ---- activation: live row r=0, 4 independent unit-chains ----
#pragma unroll
    for (int jb = 0; jb < 4; ++jb) {
      float gi = rcp_f(1.0f + EXP2(-acc[0][jb][0]));
      float gf = rcp_f(1.0f + EXP2(-acc[1][jb][0]));
      float gg = 1.0f - 2.0f * rcp_f(1.0f + EXP2(acc[2][jb][0]));
      float go = rcp_f(1.0f + EXP2(-acc[3][jb][0]));
      float cc = fmaf(gf, c4[jb], gi * gg);
      c4[jb] = cc;
      float h = go * (1.0f - 2.0f * rcp_f(1.0f + EXP2(cc * (2.0f * L2E))));
      hpl[q * 4][16 * jb + low] = bf16_rne(h);
    }

    ax = axn;
  }

  // ---- final logit from h(511) ----
  {
    const short* hp = &hpl[low][0];
    s16x8 ah0 = *(const s16x8*)(hp + q * 8);
    s16x8 ah1 = *(const s16x8*)(hp + 32 + q * 8);
    const f32x4 z = {0.f, 0.f, 0.f, 0.f};
    f32x4 aL = mfma16(ah0, wl_h[0], z);
    aL = mfma16(ah1, wl_h[1], aL);
    f32x4 bL = mfma16(ah0, wl_l[0], z);
    bL = mfma16(ah1, wl_l[1], bL);
    float lg = aL[0] + bL[0];
    if (low == 0) logitsT[NSEQ][q] = lg;
  }
  __syncthreads();

  // ---- softmax over time (all 64 lanes: 4 batches x 16 lanes) ----
  {
    const int m = q, li = low;
    float lv[32];
    float mx = -3.0e38f;
#pragma unroll
    for (int s = 0; s < 32; ++s) {
      lv[s] = logitsT[1 + li + 16 * s][m];
      mx = fmaxf(mx, lv[s]);
    }
#pragma unroll
    for (int d = 1; d < 16; d <<= 1) mx = fmaxf(mx, __shfl_xor(mx, d, 16));
    float sum = 0.f;
#pragma unroll
    for (int s = 0; s < 32; ++s) { lv[s] = __expf(lv[s] - mx); sum += lv[s]; }
#pragma unroll
    for (int d = 1; d < 16; d <<= 1) sum += __shfl_xor(sum, d, 16);
    float inv = 1.0f / sum;
#pragma unroll
    for (int s = 0; s < 32; ++s)
      out[(size_t)(b0 + m) * NSEQ + li + 16 * s] = lv[s] * inv;
  }
}

// ---------------------------------------------------------------------------
extern "C" void kernel_launch(void* const* d_in, const int* in_sizes, int n_in,
                              void* d_out, int out_size, void* d_ws, size_t ws_size,
                              hipStream_t stream) {
  const float* x      = (const float*)d_in[0];
  const float* W_fc   = (const float*)d_in[1];
  const float* b_fc   = (const float*)d_in[2];
  const float* W_ih   = (const float*)d_in[3];
  const float* W_hh   = (const float*)d_in[4];
  const float* b_ih   = (const float*)d_in[5];
  const float* b_hh   = (const float*)d_in[6];
  const float* W_last = (const float*)d_in[7];
  // d_in[8] = b_last: cancels in softmax.

  float* out = (float*)d_out;
  float* wsW = (float*)d_ws;          // 256*32 floats
  float* wsB = wsW + 256 * 32;        // 256 floats

  prep_kernel<<<8, 256, 0, stream>>>(W_fc, b_fc, W_ih, b_ih, b_hh, wsW, wsB);
  lstm_mfma<<<B_SZ / MB, 64, 0, stream>>>(x, W_hh, wsW, wsB, W_last, out);
}